// Round 1
// baseline (160.985 us; speedup 1.0000x reference)
//
#include <hip/hip_runtime.h>
#include <hip/hip_bf16.h>

typedef unsigned int u32;
typedef unsigned short u16;
using bf16x8 = __attribute__((ext_vector_type(8))) short;
using f32x4  = __attribute__((ext_vector_type(4))) float;

#define B_ 4
#define C_ 128
#define N_ 4096
#define D_ 128

__device__ __forceinline__ u16 f2bf(float f) {
    u32 x = __builtin_bit_cast(u32, f);
    x = x + 0x7fffu + ((x >> 16) & 1u);
    return (u16)(x >> 16);
}

__device__ __forceinline__ bf16x8 pack8(const float* v, float s) {
    bf16x8 r;
#pragma unroll
    for (int j = 0; j < 8; ++j) r[j] = (short)f2bf(v[j] * s);
    return r;
}

// ---------------- K1: projections ----------------
// Qbf[b][n][d] = sqrt(log2e) * sum_c Wqk[d][c] x[b][c][n]   (bf16)
// Vbf[b][d][n] = sum_c Wv[d][c] x[b][c][n] + bv[d]          (bf16)
__global__ __launch_bounds__(256) void k_proj(
        const float* __restrict__ x, const float* __restrict__ Wqk,
        const float* __restrict__ Wv, const float* __restrict__ bv,
        u16* __restrict__ Qbf, u16* __restrict__ Vbf) {
    __shared__ float xs[C_ * 65];
    const int bid = blockIdx.x;
    const int b  = bid >> 6;
    const int n0 = (bid & 63) << 6;
    const int t  = threadIdx.x;
    const float* xb = x + (size_t)b * C_ * N_;
    for (int i = 0; i < 32; ++i) {
        int idx = i * 256 + t;
        int c = idx >> 6, n = idx & 63;
        xs[c * 65 + n] = xb[(size_t)c * N_ + n0 + n];
    }
    __syncthreads();
    const int lane = t & 63, w = t >> 6;
    const int l15 = lane & 15, g = lane >> 4;
    const float SC = 1.2011224087864498f;  // sqrt(log2(e))

    bf16x8 xf[4];  // A-frag rows n = n0+16w+l15, k = c
#pragma unroll
    for (int kk = 0; kk < 4; ++kk) {
        float tmp[8];
#pragma unroll
        for (int j = 0; j < 8; ++j) tmp[j] = xs[(kk * 32 + g * 8 + j) * 65 + (16 * w + l15)];
        xf[kk] = pack8(tmp, 1.0f);
    }
    for (int dt = 0; dt < 8; ++dt) {
        const int d = dt * 16 + l15;
        bf16x8 wq[4], wv[4];
#pragma unroll
        for (int kk = 0; kk < 4; ++kk) {
            const float* pq = Wqk + (size_t)d * C_ + kk * 32 + g * 8;
            const float* pv = Wv  + (size_t)d * C_ + kk * 32 + g * 8;
            float a[8], c8[8];
#pragma unroll
            for (int j = 0; j < 8; ++j) { a[j] = pq[j]; c8[j] = pv[j]; }
            wq[kk] = pack8(a, SC);
            wv[kk] = pack8(c8, 1.0f);
        }
        f32x4 aq = {0.f, 0.f, 0.f, 0.f}, av = {0.f, 0.f, 0.f, 0.f};
#pragma unroll
        for (int kk = 0; kk < 4; ++kk) {
            aq = __builtin_amdgcn_mfma_f32_16x16x32_bf16(xf[kk], wq[kk], aq, 0, 0, 0);
            av = __builtin_amdgcn_mfma_f32_16x16x32_bf16(wv[kk], xf[kk], av, 0, 0, 0);
        }
#pragma unroll
        for (int r = 0; r < 4; ++r) {
            int nn = n0 + 16 * w + g * 4 + r;
            Qbf[((size_t)b * N_ + nn) * D_ + dt * 16 + l15] = f2bf(aq[r]);
            int dd = dt * 16 + g * 4 + r;
            Vbf[((size_t)b * D_ + dd) * N_ + n0 + 16 * w + l15] = f2bf(av[r] + bv[dd]);
        }
    }
}

// ---------------- K2: row sums of exp2(E'-64) (split over m) ----------------
__global__ __launch_bounds__(256) void k_pass1(const u16* __restrict__ Qbf,
                                               float* __restrict__ rsp) {
    __shared__ __align__(16) u16 qs[64 * 128];
    int bid = blockIdx.x;
    const int s = bid & 3; bid >>= 2;
    const int nt = bid & 63; const int b = bid >> 6;
    const int n0 = nt * 64;
    const int t = threadIdx.x, lane = t & 63, w = t >> 6;
    const int l15 = lane & 15, g = lane >> 4;

    bf16x8 af[4];  // rows n (fixed), k = d
    {
        const u16* qrow = Qbf + ((size_t)b * N_ + n0 + 16 * w + l15) * D_;
#pragma unroll
        for (int kk = 0; kk < 4; ++kk) af[kk] = *(const bf16x8*)(qrow + kk * 32 + g * 8);
    }
    float rs[4] = {0.f, 0.f, 0.f, 0.f};
    for (int mc = 0; mc < 16; ++mc) {
        const int m0 = s * 1024 + mc * 64;
        __syncthreads();
#pragma unroll
        for (int p = 0; p < 4; ++p) {   // stage 64 rows x 128 d, swizzled 16B granules
            int gi = p * 256 + t;
            int row = gi >> 4, cg = gi & 15;
            const u16* src = Qbf + ((size_t)b * N_ + m0 + row) * D_ + ((cg ^ (row & 7)) * 8);
            *(uint4*)&qs[row * 128 + cg * 8] = *(const uint4*)src;
        }
        __syncthreads();
#pragma unroll
        for (int mt = 0; mt < 4; ++mt) {
            f32x4 e = {0.f, 0.f, 0.f, 0.f};
            const int row = mt * 16 + l15;
#pragma unroll
            for (int kk = 0; kk < 4; ++kk) {
                bf16x8 bfr = *(const bf16x8*)&qs[row * 128 + (((kk * 4 + g) ^ (row & 7)) * 8)];
                e = __builtin_amdgcn_mfma_f32_16x16x32_bf16(af[kk], bfr, e, 0, 0, 0);
            }
#pragma unroll
            for (int r = 0; r < 4; ++r) rs[r] += exp2f(e[r] - 64.0f);
        }
    }
#pragma unroll
    for (int off = 1; off < 16; off <<= 1) {
#pragma unroll
        for (int r = 0; r < 4; ++r) rs[r] += __shfl_xor(rs[r], off);
    }
    if (l15 == 0) {
        float* dst = rsp + ((size_t)s * B_ + b) * N_ + n0 + 16 * w + g * 4;
#pragma unroll
        for (int r = 0; r < 4; ++r) dst[r] = rs[r];
    }
}

// ---------------- K3: irs = 1/sum_s(rsp) ----------------
__global__ void k_irs(const float* __restrict__ rsp, float* __restrict__ irs) {
    int i = blockIdx.x * 256 + threadIdx.x;
    if (i < B_ * N_) {
        float s = 0.f;
#pragma unroll
        for (int sp = 0; sp < 4; ++sp) s += rsp[(size_t)sp * B_ * N_ + i];
        irs[i] = 1.0f / s;
    }
}

// ---------------- K4: R^T partials + colsum partials (split over n) ----------------
__global__ __launch_bounds__(256) void k_pass2(
        const u16* __restrict__ Qbf, const u16* __restrict__ Vbf,
        const float* __restrict__ irs, float* __restrict__ Rp,
        float* __restrict__ csp) {
    __shared__ __align__(16) u16 qs[32 * 128];
    __shared__ __align__(16) u16 vs[128 * 32];
    __shared__ float irss[32];
    int bid = blockIdx.x;
    const int s = bid & 3; bid >>= 2;
    const int mch = bid & 63; const int b = bid >> 6;
    const int m0 = mch * 64;
    const int t = threadIdx.x, lane = t & 63, w = t >> 6;
    const int l15 = lane & 15, g = lane >> 4;

    bf16x8 bq[4];  // cols m (fixed per wave), k = d
    {
        const u16* qrow = Qbf + ((size_t)b * N_ + m0 + 16 * w + l15) * D_;
#pragma unroll
        for (int kk = 0; kk < 4; ++kk) bq[kk] = *(const bf16x8*)(qrow + kk * 32 + g * 8);
    }
    f32x4 acc[8];
#pragma unroll
    for (int i = 0; i < 8; ++i) acc[i] = (f32x4){0.f, 0.f, 0.f, 0.f};
    float cs = 0.f;
    const float* irsb = irs + (size_t)b * N_;

    for (int nc = 0; nc < 32; ++nc) {
        const int nb = s * 1024 + nc * 32;
        __syncthreads();
#pragma unroll
        for (int p = 0; p < 2; ++p) {   // Q rows nb..nb+31 (swizzled)
            int gi = p * 256 + t;
            int row = gi >> 4, cg = gi & 15;
            const u16* src = Qbf + ((size_t)b * N_ + nb + row) * D_ + ((cg ^ (row & 7)) * 8);
            *(uint4*)&qs[row * 128 + cg * 8] = *(const uint4*)src;
        }
#pragma unroll
        for (int p = 0; p < 2; ++p) {   // V[d][nb..nb+31] (swizzled)
            int gi = p * 256 + t;
            int row = gi >> 2, cg = gi & 3;
            const u16* src = Vbf + ((size_t)b * D_ + row) * N_ + nb + ((cg ^ ((row >> 1) & 3)) * 8);
            *(uint4*)&vs[row * 32 + cg * 8] = *(const uint4*)src;
        }
        if (t < 32) irss[t] = irsb[nb + t];
        __syncthreads();

        float p0[4], p1[4];
#pragma unroll
        for (int tt = 0; tt < 2; ++tt) {   // E tiles: rows n (A), cols m (B)
            f32x4 e = {0.f, 0.f, 0.f, 0.f};
            const int row = tt * 16 + l15;
#pragma unroll
            for (int kk = 0; kk < 4; ++kk) {
                bf16x8 aq = *(const bf16x8*)&qs[row * 128 + (((kk * 4 + g) ^ (row & 7)) * 8)];
                e = __builtin_amdgcn_mfma_f32_16x16x32_bf16(aq, bq[kk], e, 0, 0, 0);
            }
#pragma unroll
            for (int r = 0; r < 4; ++r) {
                float pv = exp2f(e[r] - 64.0f) * irss[tt * 16 + g * 4 + r];
                if (tt == 0) p0[r] = pv; else p1[r] = pv;
                cs += pv;
            }
        }
        // build PV B-operand fragment: lane needs P[n = 8g+j][m = l15]
        bf16x8 bpv;
#pragma unroll
        for (int j = 0; j < 8; ++j) {
            const int r = j & 3, jj = j >> 2;
            const int src = (((2 * g + jj) & 3) << 4) | l15;
            float v0 = __shfl(p0[r], src);
            float v1 = __shfl(p1[r], src);
            bpv[j] = (short)f2bf(g < 2 ? v0 : v1);
        }
#pragma unroll
        for (int dt = 0; dt < 8; ++dt) {   // R^T[d][m] += V[d][n] * P[n][m]
            const int d = dt * 16 + l15;
            bf16x8 av = *(const bf16x8*)&vs[d * 32 + ((g ^ ((d >> 1) & 3)) * 8)];
            acc[dt] = __builtin_amdgcn_mfma_f32_16x16x32_bf16(av, bpv, acc[dt], 0, 0, 0);
        }
    }
    cs += __shfl_xor(cs, 16);
    cs += __shfl_xor(cs, 32);
    if (lane < 16) csp[((size_t)s * B_ + b) * N_ + m0 + 16 * w + l15] = cs;
    float* rpb = Rp + ((size_t)s * B_ + b) * D_ * N_;
#pragma unroll
    for (int dt = 0; dt < 8; ++dt) {
#pragma unroll
        for (int r = 0; r < 4; ++r)
            rpb[(size_t)(dt * 16 + g * 4 + r) * N_ + m0 + 16 * w + l15] = acc[dt][r];
    }
}

// ---------------- K5: u = x - R*ics; out = x + relu(BN(Wt u + bt)) ----------------
__global__ __launch_bounds__(256) void k_final(
        const float* __restrict__ x, const float* __restrict__ Wt,
        const float* __restrict__ bt, const float* __restrict__ gamma,
        const float* __restrict__ beta, const float* __restrict__ rmean,
        const float* __restrict__ rvar, const float* __restrict__ Rp,
        const float* __restrict__ csp, float* __restrict__ out) {
    __shared__ float us[128 * 65];
    __shared__ float icss[64];
    const int bid = blockIdx.x;
    const int b = bid >> 6;
    const int n0 = (bid & 63) << 6;
    const int t = threadIdx.x, lane = t & 63, w = t >> 6;
    const int l15 = lane & 15, g = lane >> 4;
    if (t < 64) {
        float s = 0.f;
#pragma unroll
        for (int sp = 0; sp < 4; ++sp) s += csp[((size_t)sp * B_ + b) * N_ + n0 + t];
        icss[t] = 1.0f / (1e-9f + s);
    }
    __syncthreads();
    const float* xb = x + (size_t)b * C_ * N_;
    for (int i = 0; i < 32; ++i) {
        int idx = i * 256 + t;
        int d = idx >> 6, n = idx & 63;
        float r = 0.f;
#pragma unroll
        for (int sp = 0; sp < 4; ++sp)
            r += Rp[(((size_t)sp * B_ + b) * D_ + d) * N_ + n0 + n];
        us[d * 65 + n] = xb[(size_t)d * N_ + n0 + n] - r * icss[n];
    }
    __syncthreads();
    bf16x8 uf[4];  // B-operand: cols n = n0+16w+l15, k = d
#pragma unroll
    for (int kk = 0; kk < 4; ++kk) {
        float tmp[8];
#pragma unroll
        for (int j = 0; j < 8; ++j) tmp[j] = us[(kk * 32 + g * 8 + j) * 65 + (16 * w + l15)];
        uf[kk] = pack8(tmp, 1.0f);
    }
    for (int ct = 0; ct < 8; ++ct) {
        const int c = ct * 16 + l15;
        bf16x8 wf[4];
#pragma unroll
        for (int kk = 0; kk < 4; ++kk) {
            const float* p = Wt + (size_t)c * D_ + kk * 32 + g * 8;
            float a[8];
#pragma unroll
            for (int j = 0; j < 8; ++j) a[j] = p[j];
            wf[kk] = pack8(a, 1.0f);
        }
        f32x4 acc = {0.f, 0.f, 0.f, 0.f};
#pragma unroll
        for (int kk = 0; kk < 4; ++kk)
            acc = __builtin_amdgcn_mfma_f32_16x16x32_bf16(wf[kk], uf[kk], acc, 0, 0, 0);
#pragma unroll
        for (int r = 0; r < 4; ++r) {
            const int cc = ct * 16 + g * 4 + r;
            const int nn = n0 + 16 * w + l15;
            float y = acc[r] + bt[cc];
            float bn = gamma[cc] * (y - rmean[cc]) * rsqrtf(rvar[cc] + 1e-5f) + beta[cc];
            float rl = fmaxf(bn, 0.0f);
            out[((size_t)b * C_ + cc) * N_ + nn] = xb[(size_t)cc * N_ + nn] + rl;
        }
    }
}

extern "C" void kernel_launch(void* const* d_in, const int* in_sizes, int n_in,
                              void* d_out, int out_size, void* d_ws, size_t ws_size,
                              hipStream_t stream) {
    (void)in_sizes; (void)n_in; (void)out_size; (void)ws_size;
    const float* x     = (const float*)d_in[0];
    const float* Wqk   = (const float*)d_in[1];
    const float* Wv    = (const float*)d_in[2];
    const float* bv    = (const float*)d_in[3];
    const float* Wt    = (const float*)d_in[4];
    const float* bt    = (const float*)d_in[5];
    const float* gamma = (const float*)d_in[6];
    const float* beta  = (const float*)d_in[7];
    const float* rmean = (const float*)d_in[8];
    const float* rvar  = (const float*)d_in[9];
    float* out = (float*)d_out;

    char* ws = (char*)d_ws;
    u16*   Qbf = (u16*)(ws);                       // 4 MB
    u16*   Vbf = (u16*)(ws + 4194304);             // 4 MB
    float* rsp = (float*)(ws + 8388608);           // 256 KB
    float* irs = (float*)(ws + 8650752);           // 64 KB
    float* csp = (float*)(ws + 8716288);           // 256 KB
    float* Rp  = (float*)(ws + 8978432);           // 32 MB  (total ~42.5 MB)

    k_proj <<<B_ * 64,      256, 0, stream>>>(x, Wqk, Wv, bv, Qbf, Vbf);
    k_pass1<<<B_ * 64 * 4,  256, 0, stream>>>(Qbf, rsp);
    k_irs  <<<(B_ * N_ + 255) / 256, 256, 0, stream>>>(rsp, irs);
    k_pass2<<<B_ * 64 * 4,  256, 0, stream>>>(Qbf, Vbf, irs, Rp, csp);
    k_final<<<B_ * 64,      256, 0, stream>>>(x, Wt, bt, gamma, beta, rmean, rvar, Rp, csp, out);
}